// Round 8
// baseline (68.512 us; speedup 1.0000x reference)
//
#include <hip/hip_runtime.h>
#include <hip/hip_bf16.h>

#define DNBR   16
#define INDIM  128
#define OUTDIM 64

typedef __attribute__((ext_vector_type(8))) short bf16x8;
typedef __attribute__((ext_vector_type(4))) float f32x4;
typedef __attribute__((ext_vector_type(4))) unsigned u32x4;

union BF8 { bf16x8 v; u32x4 u; };

__device__ __forceinline__ unsigned cvt_pk_bf16(float lo, float hi) {
    unsigned r;
    asm("v_cvt_pk_bf16_f32 %0, %1, %2" : "=v"(r) : "v"(lo), "v"(hi));
    return r;
}

// ---------------- Phase 0: pre-pack W_fc into MFMA B-fragment order (bf16) ----
__global__ __launch_bounds__(256) void wprep(
    const float* __restrict__ W_fc, unsigned* __restrict__ wfrag)
{
    const int t = threadIdx.x;
    #pragma unroll
    for (int s4 = 0; s4 < 4; ++s4) {
        const int slot = t + 256 * s4;        // 0..1023
        const int lane = slot & 63;
        const int ckk  = slot >> 6;           // ct*4+kk
        const int ct = ckk >> 2, kk = ckk & 3;
        const int lm = lane & 15, lg = lane >> 4;
        const float* wr = W_fc + (size_t)(ct * 16 + lm) * INDIM + kk * 32 + lg * 8;
        const float4 w0 = *reinterpret_cast<const float4*>(wr);
        const float4 w1 = *reinterpret_cast<const float4*>(wr + 4);
        u32x4 o;
        o[0] = cvt_pk_bf16(w0.x, w0.y);
        o[1] = cvt_pk_bf16(w0.z, w0.w);
        o[2] = cvt_pk_bf16(w1.x, w1.y);
        o[3] = cvt_pk_bf16(w1.z, w1.w);
        *reinterpret_cast<u32x4*>(wfrag + (size_t)slot * 4) = o;
    }
}

// ---------------- Phase 1: z = h @ W_fc^T via bf16 MFMA (32 rows/wave) --------
__global__ __launch_bounds__(256) void fc_mfma(
    const float* __restrict__ h, const unsigned* __restrict__ wfrag,
    const float* __restrict__ W_attn, __hip_bfloat16* __restrict__ zb,
    float* __restrict__ s_src, float* __restrict__ s_dst, int n)
{
    const int lane  = threadIdx.x & 63;
    const int wid   = threadIdx.x >> 6;
    const int node0 = blockIdx.x * 128 + wid * 32;
    if (node0 >= n) return;
    const int lm = lane & 15;
    const int lg = lane >> 4;

    // shared B fragments (L1-hot 16 KB), amortized over 32 rows
    bf16x8 bfrag[4][4];
    #pragma unroll
    for (int ct = 0; ct < 4; ++ct)
        #pragma unroll
        for (int kk = 0; kk < 4; ++kk) {
            BF8 u;
            u.u = *reinterpret_cast<const u32x4*>(wfrag + (size_t)((ct * 4 + kk) * 64 + lane) * 4);
            bfrag[ct][kk] = u.v;
        }

    const int ar0 = (node0 + lm < n)      ? (node0 + lm)      : (n - 1);
    const int ar1 = (node0 + 16 + lm < n) ? (node0 + 16 + lm) : (n - 1);
    const float* h0 = h + (size_t)ar0 * INDIM;
    const float* h1 = h + (size_t)ar1 * INDIM;
    bf16x8 af0[4], af1[4];
    #pragma unroll
    for (int kk = 0; kk < 4; ++kk) {
        const float4 a0 = *reinterpret_cast<const float4*>(h0 + kk * 32 + lg * 8);
        const float4 a1 = *reinterpret_cast<const float4*>(h0 + kk * 32 + lg * 8 + 4);
        const float4 b0 = *reinterpret_cast<const float4*>(h1 + kk * 32 + lg * 8);
        const float4 b1 = *reinterpret_cast<const float4*>(h1 + kk * 32 + lg * 8 + 4);
        BF8 u, v;
        u.u[0] = cvt_pk_bf16(a0.x, a0.y);
        u.u[1] = cvt_pk_bf16(a0.z, a0.w);
        u.u[2] = cvt_pk_bf16(a1.x, a1.y);
        u.u[3] = cvt_pk_bf16(a1.z, a1.w);
        af0[kk] = u.v;
        v.u[0] = cvt_pk_bf16(b0.x, b0.y);
        v.u[1] = cvt_pk_bf16(b0.z, b0.w);
        v.u[2] = cvt_pk_bf16(b1.x, b1.y);
        v.u[3] = cvt_pk_bf16(b1.z, b1.w);
        af1[kk] = v.v;
    }

    f32x4 acc0[4], acc1[4];
    #pragma unroll
    for (int ct = 0; ct < 4; ++ct) {
        acc0[ct] = (f32x4){0.f, 0.f, 0.f, 0.f};
        acc1[ct] = (f32x4){0.f, 0.f, 0.f, 0.f};
    }
    #pragma unroll
    for (int kk = 0; kk < 4; ++kk)
        #pragma unroll
        for (int ct = 0; ct < 4; ++ct) {
            acc0[ct] = __builtin_amdgcn_mfma_f32_16x16x32_bf16(af0[kk], bfrag[ct][kk], acc0[ct], 0, 0, 0);
            acc1[ct] = __builtin_amdgcn_mfma_f32_16x16x32_bf16(af1[kk], bfrag[ct][kk], acc1[ct], 0, 0, 0);
        }

    unsigned short* zbs = reinterpret_cast<unsigned short*>(zb);
    #pragma unroll
    for (int s = 0; s < 2; ++s) {
        const int nb = node0 + s * 16;
        float ps[4] = {0.f, 0.f, 0.f, 0.f};
        float pd[4] = {0.f, 0.f, 0.f, 0.f};
        #pragma unroll
        for (int ct = 0; ct < 4; ++ct) {
            const float as = W_attn[ct * 16 + lm];
            const float ad = W_attn[OUTDIM + ct * 16 + lm];
            #pragma unroll
            for (int r = 0; r < 4; ++r) {
                const float v = s ? acc1[ct][r] : acc0[ct][r];   // C[(lg*4+r)][ct*16+lm]
                const int grow = nb + lg * 4 + r;
                if (grow < n)
                    zbs[(size_t)grow * OUTDIM + ct * 16 + lm] =
                        (unsigned short)(cvt_pk_bf16(v, v) & 0xFFFFu);
                ps[r] = fmaf(v, as, ps[r]);
                pd[r] = fmaf(v, ad, pd[r]);
            }
        }
        #pragma unroll
        for (int off = 1; off < 16; off <<= 1) {
            #pragma unroll
            for (int r = 0; r < 4; ++r) {
                ps[r] += __shfl_xor(ps[r], off, 64);
                pd[r] += __shfl_xor(pd[r], off, 64);
            }
        }
        if (lm == 0) {
            #pragma unroll
            for (int r = 0; r < 4; ++r) {
                const int grow = nb + lg * 4 + r;
                if (grow < n) { s_src[grow] = ps[r]; s_dst[grow] = pd[r]; }
            }
        }
    }
}

// ---------------- exact entmax15 over 16 values (weights = y^2) ---------------
__device__ __forceinline__ void entmax15_weights(float x[DNBR], float wout[DNBR]) {
    float mx = x[0];
    #pragma unroll
    for (int j = 1; j < DNBR; ++j) mx = fmaxf(mx, x[j]);
    #pragma unroll
    for (int j = 0; j < DNBR; ++j) x[j] -= mx;

    float xs[DNBR];
    #pragma unroll
    for (int j = 0; j < DNBR; ++j) xs[j] = x[j];
    #pragma unroll
    for (int k = 2; k <= DNBR; k <<= 1) {
        #pragma unroll
        for (int s = k >> 1; s >= 1; s >>= 1) {
            #pragma unroll
            for (int i = 0; i < DNBR; ++i) {
                int l = i ^ s;
                if (l > i) {
                    const bool up = ((i & k) == 0);
                    float a = xs[i], b = xs[l];
                    float hi = fmaxf(a, b), lo = fminf(a, b);
                    xs[i] = up ? hi : lo;
                    xs[l] = up ? lo : hi;
                }
            }
        }
    }

    float taus[DNBR];
    float cs = 0.f, css = 0.f;
    int supp = 0;
    #pragma unroll
    for (int k = 0; k < DNBR; ++k) {
        cs  += xs[k];
        css += xs[k] * xs[k];
        const float kk = (float)(k + 1);
        const float mean   = cs  / kk;
        const float meansq = css / kk;
        const float ssv    = kk * (meansq - mean * mean);
        const float delta  = (1.f - ssv) / kk;
        const float sq     = (delta > 0.f) ? sqrtf(delta) : 0.f;
        taus[k] = mean - sq;
        supp += (taus[k] <= xs[k]) ? 1 : 0;
    }
    float tau_star = taus[0];
    #pragma unroll
    for (int k = 1; k < DNBR; ++k)
        tau_star = (supp - 1 == k) ? taus[k] : tau_star;

    #pragma unroll
    for (int j = 0; j < DNBR; ++j) {
        const float y = fmaxf(x[j] - tau_star, 0.f);
        wout[j] = y * y;
    }
}

// ---------------- Phase 2: one thread per node -> alpha[n][16] ----------------
__global__ __launch_bounds__(256) void alpha_kernel(
    const int* __restrict__ nbr, const float* __restrict__ wbias,
    const float* __restrict__ s_src, const float* __restrict__ s_dst,
    float* __restrict__ alpha, int n)
{
    const int node = blockIdx.x * 256 + threadIdx.x;
    if (node >= n) return;

    const int4*   nrow = reinterpret_cast<const int4*>(nbr + (size_t)node * DNBR);
    const float4* wrow = reinterpret_cast<const float4*>(wbias + (size_t)node * DNBR);
    const float sd = s_dst[node];

    float x[DNBR];
    #pragma unroll
    for (int q = 0; q < 4; ++q) {
        const int4 v   = nrow[q];
        const float4 t = wrow[q];
        const int   nb4[4] = {v.x, v.y, v.z, v.w};
        const float w4[4]  = {t.x, t.y, t.z, t.w};
        #pragma unroll
        for (int j = 0; j < 4; ++j) {
            float e = s_src[nb4[j]] + sd;
            e = (e >= 0.f) ? e : 0.01f * e;
            x[q * 4 + j] = 0.5f * (e + w4[j]);
        }
    }

    float wts[DNBR];
    entmax15_weights(x, wts);

    float4* arow = reinterpret_cast<float4*>(alpha + (size_t)node * DNBR);
    #pragma unroll
    for (int q = 0; q < 4; ++q)
        arow[q] = make_float4(wts[q * 4 + 0], wts[q * 4 + 1], wts[q * 4 + 2], wts[q * 4 + 3]);
}

// ---------------- Phase 3: wave per 4 nodes; contiguous-slot gathers ----------
// lane = (g = lane>>4: neighbor quad, slots 4g..4g+3; c4 = lane&15: chan quad).
// Per node: 1 int4 (nbr) + 1 float4 (alpha) + 4 uint2 z-gathers = 6 VMEM.
// Reduce over g via shfl_xor(16,32); lanes g==0 store coalesced float4.
__global__ __launch_bounds__(256) void out_kernel(
    const int* __restrict__ nbr, const float* __restrict__ alpha,
    const __hip_bfloat16* __restrict__ zb, float* __restrict__ out, int n)
{
    const int lane = threadIdx.x & 63;
    const int wv   = blockIdx.x * 4 + (threadIdx.x >> 6);
    const int base = wv * 4;
    if (base >= n) return;
    const int g  = lane >> 4;
    const int c4 = lane & 15;
    const unsigned short* zs = reinterpret_cast<const unsigned short*>(zb);

    #pragma unroll
    for (int i = 0; i < 4; ++i) {
        const int node = base + i;
        const int ni = (node < n) ? node : n - 1;   // clamp loads; store guarded
        const int4   nb = *reinterpret_cast<const int4*>(nbr + (size_t)ni * DNBR + 4 * g);
        const float4 aw = *reinterpret_cast<const float4*>(alpha + (size_t)ni * DNBR + 4 * g);
        const uint2 z0 = *reinterpret_cast<const uint2*>(zs + (size_t)nb.x * OUTDIM + c4 * 4);
        const uint2 z1 = *reinterpret_cast<const uint2*>(zs + (size_t)nb.y * OUTDIM + c4 * 4);
        const uint2 z2 = *reinterpret_cast<const uint2*>(zs + (size_t)nb.z * OUTDIM + c4 * 4);
        const uint2 z3 = *reinterpret_cast<const uint2*>(zs + (size_t)nb.w * OUTDIM + c4 * 4);

        float a0 = 0.f, a1 = 0.f, a2 = 0.f, a3 = 0.f;
        union { unsigned u; float f; } w;
        #define ACC(av, zv)                                        \
            w.u = (zv).x << 16;         a0 = fmaf(av, w.f, a0);    \
            w.u = (zv).x & 0xFFFF0000u; a1 = fmaf(av, w.f, a1);    \
            w.u = (zv).y << 16;         a2 = fmaf(av, w.f, a2);    \
            w.u = (zv).y & 0xFFFF0000u; a3 = fmaf(av, w.f, a3);
        ACC(aw.x, z0) ACC(aw.y, z1) ACC(aw.z, z2) ACC(aw.w, z3)
        #undef ACC

        a0 += __shfl_xor(a0, 16, 64);  a0 += __shfl_xor(a0, 32, 64);
        a1 += __shfl_xor(a1, 16, 64);  a1 += __shfl_xor(a1, 32, 64);
        a2 += __shfl_xor(a2, 16, 64);  a2 += __shfl_xor(a2, 32, 64);
        a3 += __shfl_xor(a3, 16, 64);  a3 += __shfl_xor(a3, 32, 64);

        if (g == 0 && node < n)
            *reinterpret_cast<float4*>(out + (size_t)node * OUTDIM + c4 * 4) =
                make_float4(a0, a1, a2, a3);
    }
}

extern "C" void kernel_launch(void* const* d_in, const int* in_sizes, int n_in,
                              void* d_out, int out_size, void* d_ws, size_t ws_size,
                              hipStream_t stream) {
    const float* h      = (const float*)d_in[0];
    const int*   nbr    = (const int*)  d_in[1];
    const float* wbias  = (const float*)d_in[2];
    const float* W_fc   = (const float*)d_in[3];
    const float* W_attn = (const float*)d_in[4];
    float* out = (float*)d_out;

    const int n = in_sizes[0] / INDIM;   // 100000

    // ws: zb (n*64 bf16) | s_src (n f32) | s_dst (n f32) | alpha (n*16 f32) | wfrag (4096 u32)
    __hip_bfloat16* zb = (__hip_bfloat16*)d_ws;
    float* s_src = (float*)((char*)d_ws + (size_t)n * OUTDIM * sizeof(__hip_bfloat16));
    float* s_dst = s_src + n;
    float* alpha = s_dst + n;
    unsigned* wfrag = (unsigned*)(alpha + (size_t)n * DNBR);

    wprep<<<1, 256, 0, stream>>>(W_fc, wfrag);
    fc_mfma<<<(n + 127) / 128, 256, 0, stream>>>(h, wfrag, W_attn, zb, s_src, s_dst, n);
    alpha_kernel<<<(n + 255) / 256, 256, 0, stream>>>(nbr, wbias, s_src, s_dst, alpha, n);
    out_kernel<<<(n + 15) / 16, 256, 0, stream>>>(nbr, alpha, zb, out, n);
}

// Round 9
// 67.347 us; speedup vs baseline: 1.0173x; 1.0173x over previous
//
#include <hip/hip_runtime.h>
#include <hip/hip_bf16.h>

#define DNBR   16
#define INDIM  128
#define OUTDIM 64

typedef __attribute__((ext_vector_type(8))) short bf16x8;
typedef __attribute__((ext_vector_type(4))) float f32x4;
typedef __attribute__((ext_vector_type(4))) unsigned u32x4;

union BF8 { bf16x8 v; u32x4 u; };

__device__ __forceinline__ unsigned cvt_pk_bf16(float lo, float hi) {
    unsigned r;
    asm("v_cvt_pk_bf16_f32 %0, %1, %2" : "=v"(r) : "v"(lo), "v"(hi));
    return r;
}

// ---------------- Phase 1: z = h @ W_fc^T via bf16 MFMA, + s_src/s_dst -------
// W_fc converted to MFMA B-fragment order in LDS per block (no wprep kernel).
// One wave = 16 rows x 64 cols.
__global__ __launch_bounds__(256) void fc_mfma(
    const float* __restrict__ h, const float* __restrict__ W_fc,
    const float* __restrict__ W_attn, __hip_bfloat16* __restrict__ zb,
    float* __restrict__ s_src, float* __restrict__ s_dst, int n)
{
    __shared__ unsigned wl[4096];   // 16 KB: slot(ct,kk,lane) -> 4 u32 (8 bf16)

    const int tid = threadIdx.x;
    #pragma unroll
    for (int s4 = 0; s4 < 4; ++s4) {
        const int slot = tid + 256 * s4;      // 0..1023
        const int lane_s = slot & 63;
        const int ckk  = slot >> 6;           // ct*4+kk
        const int ct_s = ckk >> 2, kk_s = ckk & 3;
        const int lm_s = lane_s & 15, lg_s = lane_s >> 4;
        const float* wr = W_fc + (size_t)(ct_s * 16 + lm_s) * INDIM + kk_s * 32 + lg_s * 8;
        const float4 w0 = *reinterpret_cast<const float4*>(wr);
        const float4 w1 = *reinterpret_cast<const float4*>(wr + 4);
        wl[slot * 4 + 0] = cvt_pk_bf16(w0.x, w0.y);
        wl[slot * 4 + 1] = cvt_pk_bf16(w0.z, w0.w);
        wl[slot * 4 + 2] = cvt_pk_bf16(w1.x, w1.y);
        wl[slot * 4 + 3] = cvt_pk_bf16(w1.z, w1.w);
    }
    __syncthreads();

    const int lane  = threadIdx.x & 63;
    const int wid   = threadIdx.x >> 6;
    const int node0 = blockIdx.x * 64 + wid * 16;
    if (node0 >= n) return;
    const int lm = lane & 15;
    const int lg = lane >> 4;

    bf16x8 bfrag[4][4];
    #pragma unroll
    for (int ct = 0; ct < 4; ++ct)
        #pragma unroll
        for (int kk = 0; kk < 4; ++kk) {
            BF8 u;
            u.u = *reinterpret_cast<const u32x4*>(&wl[(size_t)((ct * 4 + kk) * 64 + lane) * 4]);
            bfrag[ct][kk] = u.v;
        }

    const int arow = (node0 + lm < n) ? (node0 + lm) : (n - 1);
    const float* hr = h + (size_t)arow * INDIM;
    bf16x8 af[4];
    #pragma unroll
    for (int kk = 0; kk < 4; ++kk) {
        const float4 a0 = *reinterpret_cast<const float4*>(hr + kk * 32 + lg * 8);
        const float4 a1 = *reinterpret_cast<const float4*>(hr + kk * 32 + lg * 8 + 4);
        BF8 u;
        u.u[0] = cvt_pk_bf16(a0.x, a0.y);
        u.u[1] = cvt_pk_bf16(a0.z, a0.w);
        u.u[2] = cvt_pk_bf16(a1.x, a1.y);
        u.u[3] = cvt_pk_bf16(a1.z, a1.w);
        af[kk] = u.v;
    }

    f32x4 acc[4];
    #pragma unroll
    for (int ct = 0; ct < 4; ++ct) acc[ct] = (f32x4){0.f, 0.f, 0.f, 0.f};
    #pragma unroll
    for (int kk = 0; kk < 4; ++kk)
        #pragma unroll
        for (int ct = 0; ct < 4; ++ct)
            acc[ct] = __builtin_amdgcn_mfma_f32_16x16x32_bf16(af[kk], bfrag[ct][kk], acc[ct], 0, 0, 0);

    float ps[4] = {0.f, 0.f, 0.f, 0.f};
    float pd[4] = {0.f, 0.f, 0.f, 0.f};
    unsigned short* zbs = reinterpret_cast<unsigned short*>(zb);
    #pragma unroll
    for (int ct = 0; ct < 4; ++ct) {
        const float as = W_attn[ct * 16 + lm];
        const float ad = W_attn[OUTDIM + ct * 16 + lm];
        #pragma unroll
        for (int r = 0; r < 4; ++r) {
            const float v = acc[ct][r];                 // C[(lg*4+r)][ct*16+lm]
            const int grow = node0 + lg * 4 + r;
            if (grow < n)
                zbs[(size_t)grow * OUTDIM + ct * 16 + lm] =
                    (unsigned short)(cvt_pk_bf16(v, v) & 0xFFFFu);
            ps[r] = fmaf(v, as, ps[r]);
            pd[r] = fmaf(v, ad, pd[r]);
        }
    }
    #pragma unroll
    for (int off = 1; off < 16; off <<= 1) {
        #pragma unroll
        for (int r = 0; r < 4; ++r) {
            ps[r] += __shfl_xor(ps[r], off, 64);
            pd[r] += __shfl_xor(pd[r], off, 64);
        }
    }
    if (lm == 0) {
        #pragma unroll
        for (int r = 0; r < 4; ++r) {
            const int grow = node0 + lg * 4 + r;
            if (grow < n) { s_src[grow] = ps[r]; s_dst[grow] = pd[r]; }
        }
    }
}

// ---------------- exact entmax15 over 16 values (weights = y^2) ---------------
__device__ __forceinline__ void entmax15_weights(float x[DNBR], float wout[DNBR]) {
    float mx = x[0];
    #pragma unroll
    for (int j = 1; j < DNBR; ++j) mx = fmaxf(mx, x[j]);
    #pragma unroll
    for (int j = 0; j < DNBR; ++j) x[j] -= mx;

    float xs[DNBR];
    #pragma unroll
    for (int j = 0; j < DNBR; ++j) xs[j] = x[j];
    #pragma unroll
    for (int k = 2; k <= DNBR; k <<= 1) {
        #pragma unroll
        for (int s = k >> 1; s >= 1; s >>= 1) {
            #pragma unroll
            for (int i = 0; i < DNBR; ++i) {
                int l = i ^ s;
                if (l > i) {
                    const bool up = ((i & k) == 0);
                    float a = xs[i], b = xs[l];
                    float hi = fmaxf(a, b), lo = fminf(a, b);
                    xs[i] = up ? hi : lo;
                    xs[l] = up ? lo : hi;
                }
            }
        }
    }

    float taus[DNBR];
    float cs = 0.f, css = 0.f;
    int supp = 0;
    #pragma unroll
    for (int k = 0; k < DNBR; ++k) {
        cs  += xs[k];
        css += xs[k] * xs[k];
        const float kk = (float)(k + 1);
        const float mean   = cs  / kk;
        const float meansq = css / kk;
        const float ssv    = kk * (meansq - mean * mean);
        const float delta  = (1.f - ssv) / kk;
        const float sq     = (delta > 0.f) ? sqrtf(delta) : 0.f;
        taus[k] = mean - sq;
        supp += (taus[k] <= xs[k]) ? 1 : 0;
    }
    float tau_star = taus[0];
    #pragma unroll
    for (int k = 1; k < DNBR; ++k)
        tau_star = (supp - 1 == k) ? taus[k] : tau_star;

    #pragma unroll
    for (int j = 0; j < DNBR; ++j) {
        const float y = fmaxf(x[j] - tau_star, 0.f);
        wout[j] = y * y;
    }
}

// ---------------- Phase 2: one thread per node -> alpha[n][16] ----------------
__global__ __launch_bounds__(256) void alpha_kernel(
    const int* __restrict__ nbr, const float* __restrict__ wbias,
    const float* __restrict__ s_src, const float* __restrict__ s_dst,
    float* __restrict__ alpha, int n)
{
    const int node = blockIdx.x * 256 + threadIdx.x;
    if (node >= n) return;

    const int4*   nrow = reinterpret_cast<const int4*>(nbr + (size_t)node * DNBR);
    const float4* wrow = reinterpret_cast<const float4*>(wbias + (size_t)node * DNBR);
    const float sd = s_dst[node];

    float x[DNBR];
    #pragma unroll
    for (int q = 0; q < 4; ++q) {
        const int4 v   = nrow[q];
        const float4 t = wrow[q];
        const int   nb4[4] = {v.x, v.y, v.z, v.w};
        const float w4[4]  = {t.x, t.y, t.z, t.w};
        #pragma unroll
        for (int j = 0; j < 4; ++j) {
            float e = s_src[nb4[j]] + sd;
            e = (e >= 0.f) ? e : 0.01f * e;
            x[q * 4 + j] = 0.5f * (e + w4[j]);
        }
    }

    float wts[DNBR];
    entmax15_weights(x, wts);

    float4* arow = reinterpret_cast<float4*>(alpha + (size_t)node * DNBR);
    #pragma unroll
    for (int q = 0; q < 4; ++q)
        arow[q] = make_float4(wts[q * 4 + 0], wts[q * 4 + 1], wts[q * 4 + 2], wts[q * 4 + 3]);
}

// ---------------- Phase 3: wave per 4 nodes; dwordx4 gathers (2/node) ---------
// lane = (g = lane>>3: row slot; c8 = lane&7: channel octet).
// Gather t covers rows {8t+g}: 8 rows x 128B per instruction, 16B/lane.
// Reduce over g via shfl_xor(8,16,32); lanes g==0 store 2x float4.
__global__ __launch_bounds__(256) void out_kernel(
    const int* __restrict__ nbr, const float* __restrict__ alpha,
    const __hip_bfloat16* __restrict__ zb, float* __restrict__ out, int n)
{
    const int lane = threadIdx.x & 63;
    const int wv   = blockIdx.x * 4 + (threadIdx.x >> 6);
    const int base = wv * 4;
    if (base >= n) return;
    const int g  = lane >> 3;
    const int c8 = lane & 7;
    const unsigned short* zs = reinterpret_cast<const unsigned short*>(zb);

    #pragma unroll
    for (int i = 0; i < 4; ++i) {
        const int node = base + i;
        const int ni = (node < n) ? node : n - 1;   // clamp loads; store guarded

        const int   j0 = nbr  [(size_t)ni * DNBR + g];
        const int   j1 = nbr  [(size_t)ni * DNBR + 8 + g];
        const float a0w = alpha[(size_t)ni * DNBR + g];
        const float a1w = alpha[(size_t)ni * DNBR + 8 + g];

        const u32x4 z0 = *reinterpret_cast<const u32x4*>(zs + (size_t)j0 * OUTDIM + c8 * 8);
        const u32x4 z1 = *reinterpret_cast<const u32x4*>(zs + (size_t)j1 * OUTDIM + c8 * 8);

        float acc[8] = {0.f, 0.f, 0.f, 0.f, 0.f, 0.f, 0.f, 0.f};
        union { unsigned u; float f; } w;
        #define ACC2(av, zv)                                               \
            w.u = (zv)[0] << 16;         acc[0] = fmaf(av, w.f, acc[0]);   \
            w.u = (zv)[0] & 0xFFFF0000u; acc[1] = fmaf(av, w.f, acc[1]);   \
            w.u = (zv)[1] << 16;         acc[2] = fmaf(av, w.f, acc[2]);   \
            w.u = (zv)[1] & 0xFFFF0000u; acc[3] = fmaf(av, w.f, acc[3]);   \
            w.u = (zv)[2] << 16;         acc[4] = fmaf(av, w.f, acc[4]);   \
            w.u = (zv)[2] & 0xFFFF0000u; acc[5] = fmaf(av, w.f, acc[5]);   \
            w.u = (zv)[3] << 16;         acc[6] = fmaf(av, w.f, acc[6]);   \
            w.u = (zv)[3] & 0xFFFF0000u; acc[7] = fmaf(av, w.f, acc[7]);
        ACC2(a0w, z0)
        ACC2(a1w, z1)
        #undef ACC2

        #pragma unroll
        for (int c = 0; c < 8; ++c) {
            acc[c] += __shfl_xor(acc[c], 8, 64);
            acc[c] += __shfl_xor(acc[c], 16, 64);
            acc[c] += __shfl_xor(acc[c], 32, 64);
        }

        if (g == 0 && node < n) {
            float* orow = out + (size_t)node * OUTDIM + c8 * 8;
            *reinterpret_cast<float4*>(orow)     = make_float4(acc[0], acc[1], acc[2], acc[3]);
            *reinterpret_cast<float4*>(orow + 4) = make_float4(acc[4], acc[5], acc[6], acc[7]);
        }
    }
}

extern "C" void kernel_launch(void* const* d_in, const int* in_sizes, int n_in,
                              void* d_out, int out_size, void* d_ws, size_t ws_size,
                              hipStream_t stream) {
    const float* h      = (const float*)d_in[0];
    const int*   nbr    = (const int*)  d_in[1];
    const float* wbias  = (const float*)d_in[2];
    const float* W_fc   = (const float*)d_in[3];
    const float* W_attn = (const float*)d_in[4];
    float* out = (float*)d_out;

    const int n = in_sizes[0] / INDIM;   // 100000

    // ws: zb (n*64 bf16) | s_src (n f32) | s_dst (n f32) | alpha (n*16 f32)
    __hip_bfloat16* zb = (__hip_bfloat16*)d_ws;
    float* s_src = (float*)((char*)d_ws + (size_t)n * OUTDIM * sizeof(__hip_bfloat16));
    float* s_dst = s_src + n;
    float* alpha = s_dst + n;

    fc_mfma<<<(n + 63) / 64, 256, 0, stream>>>(h, W_fc, W_attn, zb, s_src, s_dst, n);
    alpha_kernel<<<(n + 255) / 256, 256, 0, stream>>>(nbr, wbias, s_src, s_dst, alpha, n);
    out_kernel<<<(n + 15) / 16, 256, 0, stream>>>(nbr, alpha, zb, out, n);
}

// Round 10
// 59.580 us; speedup vs baseline: 1.1499x; 1.1304x over previous
//
#include <hip/hip_runtime.h>
#include <hip/hip_bf16.h>

#define DNBR   16
#define INDIM  128
#define OUTDIM 64

typedef __attribute__((ext_vector_type(8))) short bf16x8;
typedef __attribute__((ext_vector_type(4))) float f32x4;
typedef __attribute__((ext_vector_type(4))) unsigned u32x4;

union BF8 { bf16x8 v; u32x4 u; };

__device__ __forceinline__ unsigned cvt_pk_bf16(float lo, float hi) {
    unsigned r;
    asm("v_cvt_pk_bf16_f32 %0, %1, %2" : "=v"(r) : "v"(lo), "v"(hi));
    return r;
}

// ---------------- Phase 1: z = h @ W_fc^T via bf16 MFMA, + s_src/s_dst -------
// W_fc converted to MFMA B-fragment order in LDS per block.
__global__ __launch_bounds__(256) void fc_mfma(
    const float* __restrict__ h, const float* __restrict__ W_fc,
    const float* __restrict__ W_attn, __hip_bfloat16* __restrict__ zb,
    float* __restrict__ s_src, float* __restrict__ s_dst, int n)
{
    __shared__ unsigned wl[4096];   // 16 KB: slot(ct,kk,lane) -> 4 u32 (8 bf16)

    const int tid = threadIdx.x;
    #pragma unroll
    for (int s4 = 0; s4 < 4; ++s4) {
        const int slot = tid + 256 * s4;      // 0..1023
        const int lane_s = slot & 63;
        const int ckk  = slot >> 6;           // ct*4+kk
        const int ct_s = ckk >> 2, kk_s = ckk & 3;
        const int lm_s = lane_s & 15, lg_s = lane_s >> 4;
        const float* wr = W_fc + (size_t)(ct_s * 16 + lm_s) * INDIM + kk_s * 32 + lg_s * 8;
        const float4 w0 = *reinterpret_cast<const float4*>(wr);
        const float4 w1 = *reinterpret_cast<const float4*>(wr + 4);
        wl[slot * 4 + 0] = cvt_pk_bf16(w0.x, w0.y);
        wl[slot * 4 + 1] = cvt_pk_bf16(w0.z, w0.w);
        wl[slot * 4 + 2] = cvt_pk_bf16(w1.x, w1.y);
        wl[slot * 4 + 3] = cvt_pk_bf16(w1.z, w1.w);
    }
    __syncthreads();

    const int lane  = threadIdx.x & 63;
    const int wid   = threadIdx.x >> 6;
    const int node0 = blockIdx.x * 64 + wid * 16;
    if (node0 >= n) return;
    const int lm = lane & 15;
    const int lg = lane >> 4;

    bf16x8 bfrag[4][4];
    #pragma unroll
    for (int ct = 0; ct < 4; ++ct)
        #pragma unroll
        for (int kk = 0; kk < 4; ++kk) {
            BF8 u;
            u.u = *reinterpret_cast<const u32x4*>(&wl[(size_t)((ct * 4 + kk) * 64 + lane) * 4]);
            bfrag[ct][kk] = u.v;
        }

    const int arow = (node0 + lm < n) ? (node0 + lm) : (n - 1);
    const float* hr = h + (size_t)arow * INDIM;
    bf16x8 af[4];
    #pragma unroll
    for (int kk = 0; kk < 4; ++kk) {
        const float4 a0 = *reinterpret_cast<const float4*>(hr + kk * 32 + lg * 8);
        const float4 a1 = *reinterpret_cast<const float4*>(hr + kk * 32 + lg * 8 + 4);
        BF8 u;
        u.u[0] = cvt_pk_bf16(a0.x, a0.y);
        u.u[1] = cvt_pk_bf16(a0.z, a0.w);
        u.u[2] = cvt_pk_bf16(a1.x, a1.y);
        u.u[3] = cvt_pk_bf16(a1.z, a1.w);
        af[kk] = u.v;
    }

    f32x4 acc[4];
    #pragma unroll
    for (int ct = 0; ct < 4; ++ct) acc[ct] = (f32x4){0.f, 0.f, 0.f, 0.f};
    #pragma unroll
    for (int kk = 0; kk < 4; ++kk)
        #pragma unroll
        for (int ct = 0; ct < 4; ++ct)
            acc[ct] = __builtin_amdgcn_mfma_f32_16x16x32_bf16(af[kk], bfrag[ct][kk], acc[ct], 0, 0, 0);

    float ps[4] = {0.f, 0.f, 0.f, 0.f};
    float pd[4] = {0.f, 0.f, 0.f, 0.f};
    unsigned short* zbs = reinterpret_cast<unsigned short*>(zb);
    #pragma unroll
    for (int ct = 0; ct < 4; ++ct) {
        const float as = W_attn[ct * 16 + lm];
        const float ad = W_attn[OUTDIM + ct * 16 + lm];
        #pragma unroll
        for (int r = 0; r < 4; ++r) {
            const float v = acc[ct][r];                 // C[(lg*4+r)][ct*16+lm]
            const int grow = node0 + lg * 4 + r;
            if (grow < n)
                zbs[(size_t)grow * OUTDIM + ct * 16 + lm] =
                    (unsigned short)(cvt_pk_bf16(v, v) & 0xFFFFu);
            ps[r] = fmaf(v, as, ps[r]);
            pd[r] = fmaf(v, ad, pd[r]);
        }
    }
    #pragma unroll
    for (int off = 1; off < 16; off <<= 1) {
        #pragma unroll
        for (int r = 0; r < 4; ++r) {
            ps[r] += __shfl_xor(ps[r], off, 64);
            pd[r] += __shfl_xor(pd[r], off, 64);
        }
    }
    if (lm == 0) {
        #pragma unroll
        for (int r = 0; r < 4; ++r) {
            const int grow = node0 + lg * 4 + r;
            if (grow < n) { s_src[grow] = ps[r]; s_dst[grow] = pd[r]; }
        }
    }
}

// ---------------- Phase 2: fused lane-parallel entmax + gather ---------------
// Wave handles 4 nodes. Entmax: 16-lane group per node (bitonic sort across
// lanes + shfl scans + ballot support count) -> weights to per-wave LDS.
// Gather: identical structure to R9 (g=lane>>3 row slot, c8=lane&7 chan octet,
// 2x dwordx4 gathers per node).
__global__ __launch_bounds__(256) void fused_out(
    const int* __restrict__ nbr, const float* __restrict__ wbias,
    const __hip_bfloat16* __restrict__ zb, const float* __restrict__ s_src,
    const float* __restrict__ s_dst, float* __restrict__ out, int n)
{
    __shared__ float w_lds[4][64];
    __shared__ int  nb_lds[4][64];

    const int lane = threadIdx.x & 63;
    const int wid  = threadIdx.x >> 6;
    const int wv   = blockIdx.x * 4 + wid;
    const int base = wv * 4;
    if (base >= n) return;

    // ---- entmax phase: group q = lane>>4 handles node base+q, slot j=lane&15
    {
        const int q = lane >> 4;
        const int j = lane & 15;
        const int gb = lane & 48;            // group base lane
        const int node_q = base + q;
        const int nq = (node_q < n) ? node_q : n - 1;

        const int   nbj = nbr  [(size_t)nq * DNBR + j];
        const float wj  = wbias[(size_t)nq * DNBR + j];
        const float sd  = s_dst[nq];
        float e = s_src[nbj] + sd;
        e = (e >= 0.f) ? e : 0.01f * e;
        float x = 0.5f * (e + wj);

        // group max, subtract
        float m = x;
        m = fmaxf(m, __shfl_xor(m, 1, 64));
        m = fmaxf(m, __shfl_xor(m, 2, 64));
        m = fmaxf(m, __shfl_xor(m, 4, 64));
        m = fmaxf(m, __shfl_xor(m, 8, 64));
        x -= m;

        // bitonic sort DESCENDING across the 16-lane group (all dirs flipped)
        float v = x;
        #pragma unroll
        for (int k = 2; k <= 16; k <<= 1) {
            #pragma unroll
            for (int s = k >> 1; s >= 1; s >>= 1) {
                const float other = __shfl_xor(v, s, 64);
                const bool lower = ((j & s) == 0);
                const bool up    = ((j & k) == 0);
                v = (lower == up) ? fmaxf(v, other) : fminf(v, other);
            }
        }

        // inclusive scans of v and v^2 over ranks 0..j
        float cs = v, css = v * v;
        #pragma unroll
        for (int off = 1; off < 16; off <<= 1) {
            const int src = gb + ((j >= off) ? (j - off) : 0);
            const float t1 = __shfl(cs,  src, 64);
            const float t2 = __shfl(css, src, 64);
            if (j >= off) { cs += t1; css += t2; }
        }

        const float kkf    = (float)(j + 1);
        const float mean   = cs / kkf;
        const float meansq = css / kkf;
        const float ssv    = kkf * (meansq - mean * mean);
        const float delta  = (1.f - ssv) / kkf;
        const float sq     = (delta > 0.f) ? sqrtf(delta) : 0.f;
        const float tau    = mean - sq;

        const unsigned long long bal = __ballot(tau <= v);
        const int supp = (int)__popcll((bal >> gb) & 0xFFFFull);
        const float tau_star = __shfl(tau, gb + supp - 1, 64);

        const float y = fmaxf(x - tau_star, 0.f);
        w_lds[wid][lane]  = y * y;
        nb_lds[wid][lane] = nbj;
    }
    // same-wave LDS handoff (DS ops in program order within a wave)

    // ---- gather phase (R9 structure)
    const int g  = lane >> 3;
    const int c8 = lane & 7;
    const unsigned short* zs = reinterpret_cast<const unsigned short*>(zb);

    #pragma unroll
    for (int i = 0; i < 4; ++i) {
        const int node = base + i;

        const int   j0  = nb_lds[wid][i * 16 + g];
        const int   j1  = nb_lds[wid][i * 16 + 8 + g];
        const float a0w = w_lds[wid][i * 16 + g];
        const float a1w = w_lds[wid][i * 16 + 8 + g];

        const u32x4 z0 = *reinterpret_cast<const u32x4*>(zs + (size_t)j0 * OUTDIM + c8 * 8);
        const u32x4 z1 = *reinterpret_cast<const u32x4*>(zs + (size_t)j1 * OUTDIM + c8 * 8);

        float acc[8] = {0.f, 0.f, 0.f, 0.f, 0.f, 0.f, 0.f, 0.f};
        union { unsigned u; float f; } w;
        #define ACC2(av, zv)                                               \
            w.u = (zv)[0] << 16;         acc[0] = fmaf(av, w.f, acc[0]);   \
            w.u = (zv)[0] & 0xFFFF0000u; acc[1] = fmaf(av, w.f, acc[1]);   \
            w.u = (zv)[1] << 16;         acc[2] = fmaf(av, w.f, acc[2]);   \
            w.u = (zv)[1] & 0xFFFF0000u; acc[3] = fmaf(av, w.f, acc[3]);   \
            w.u = (zv)[2] << 16;         acc[4] = fmaf(av, w.f, acc[4]);   \
            w.u = (zv)[2] & 0xFFFF0000u; acc[5] = fmaf(av, w.f, acc[5]);   \
            w.u = (zv)[3] << 16;         acc[6] = fmaf(av, w.f, acc[6]);   \
            w.u = (zv)[3] & 0xFFFF0000u; acc[7] = fmaf(av, w.f, acc[7]);
        ACC2(a0w, z0)
        ACC2(a1w, z1)
        #undef ACC2

        #pragma unroll
        for (int c = 0; c < 8; ++c) {
            acc[c] += __shfl_xor(acc[c], 8, 64);
            acc[c] += __shfl_xor(acc[c], 16, 64);
            acc[c] += __shfl_xor(acc[c], 32, 64);
        }

        if (g == 0 && node < n) {
            float* orow = out + (size_t)node * OUTDIM + c8 * 8;
            *reinterpret_cast<float4*>(orow)     = make_float4(acc[0], acc[1], acc[2], acc[3]);
            *reinterpret_cast<float4*>(orow + 4) = make_float4(acc[4], acc[5], acc[6], acc[7]);
        }
    }
}

extern "C" void kernel_launch(void* const* d_in, const int* in_sizes, int n_in,
                              void* d_out, int out_size, void* d_ws, size_t ws_size,
                              hipStream_t stream) {
    const float* h      = (const float*)d_in[0];
    const int*   nbr    = (const int*)  d_in[1];
    const float* wbias  = (const float*)d_in[2];
    const float* W_fc   = (const float*)d_in[3];
    const float* W_attn = (const float*)d_in[4];
    float* out = (float*)d_out;

    const int n = in_sizes[0] / INDIM;   // 100000

    // ws: zb (n*64 bf16) | s_src (n f32) | s_dst (n f32)
    __hip_bfloat16* zb = (__hip_bfloat16*)d_ws;
    float* s_src = (float*)((char*)d_ws + (size_t)n * OUTDIM * sizeof(__hip_bfloat16));
    float* s_dst = s_src + n;

    fc_mfma<<<(n + 63) / 64, 256, 0, stream>>>(h, W_fc, W_attn, zb, s_src, s_dst, n);
    fused_out<<<(n + 15) / 16, 256, 0, stream>>>(nbr, wbias, zb, s_src, s_dst, out, n);
}